// Round 1
// baseline (1183.586 us; speedup 1.0000x reference)
//
#include <hip/hip_runtime.h>
#include <cstdint>
#include <cstddef>

// Problem constants: B=32, L=2048, D=1024, E=2048
#define B_ 32
#define L_ 2048
#define D_ 1024
#define E_ 2048
// GEMM view: M = B*L = 65536 rows (b,l), N = D = 1024, K = E = 2048

typedef __attribute__((ext_vector_type(8))) short short8;
typedef __attribute__((ext_vector_type(4))) float f32x4;
typedef __attribute__((ext_vector_type(4))) unsigned int uint4v;

// ---- async global->LDS, 16B per lane; LDS dest = uniform base + lane*16 ----
__device__ __forceinline__ void async_copy16(const void* g, void* l) {
  __builtin_amdgcn_global_load_lds((const __attribute__((address_space(1))) void*)g,
                                   (__attribute__((address_space(3))) void*)l, 16, 0, 0);
}

// pack two fp32 -> bf16x2 (round-half-up: add 0x8000, take hi16) ~4 VALU
__device__ __forceinline__ unsigned int pack_bf16_2(float lo, float hi) {
  unsigned int ul = __builtin_bit_cast(unsigned int, lo) + 0x8000u;
  unsigned int uh = __builtin_bit_cast(unsigned int, hi) + 0x8000u;
  return (ul >> 16) | (uh & 0xFFFF0000u);
}

__device__ __forceinline__ float fast_tanh(float x) {
  // tanh(x) = 1 - 2/(exp(2x)+1); exp overflow -> +1, underflow -> -1 (correct)
  float e = __expf(2.0f * x);
  return 1.0f - 2.0f / (e + 1.0f);
}

// ---------------- kernel 1: s[b][i] = sum_d dec[b][d] * Ws[i][d] ------------
__global__ __launch_bounds__(256) void k_s(const float* __restrict__ dec,
                                           const float* __restrict__ Ws,
                                           float* __restrict__ s) {
  int wid = threadIdx.x >> 6, lane = threadIdx.x & 63;
  int out = blockIdx.x * 4 + wid;            // 0..32767
  int b = out >> 10, i = out & 1023;
  const float* dr = dec + b * D_;
  const float* wr = Ws + (size_t)i * D_;
  float acc = 0.f;
#pragma unroll
  for (int c = 0; c < 4; ++c) {
    int d0 = c * 256 + lane * 4;
    float4 x = *(const float4*)(dr + d0);
    float4 w = *(const float4*)(wr + d0);
    acc += x.x * w.x + x.y * w.y + x.z * w.z + x.w * w.w;
  }
#pragma unroll
  for (int off = 32; off >= 1; off >>= 1) acc += __shfl_xor(acc, off, 64);
  if (lane == 0) s[out] = acc;
}

// ---------------- kernel 2: W_h fp32 -> bf16 (2M elements) ------------------
__global__ __launch_bounds__(256) void k_cvt(const float* __restrict__ src,
                                             unsigned short* __restrict__ dst) {
  size_t i = ((size_t)blockIdx.x * 256 + threadIdx.x) * 8;
  float4 a = *(const float4*)(src + i);
  float4 b = *(const float4*)(src + i + 4);
  uint4v p;
  p.x = pack_bf16_2(a.x, a.y);
  p.y = pack_bf16_2(a.z, a.w);
  p.z = pack_bf16_2(b.x, b.y);
  p.w = pack_bf16_2(b.z, b.w);
  *(uint4v*)(dst + i) = p;
}

// ---------------- kernel 3: fused GEMM + tanh + v-dot -----------------------
// scores[m] = sum_n v[n] * tanh(s[b][n] + sum_k enc[m][k]*Whb[n][k]),  m=(b,l)
// BM=128, BN=128, BK=32; 256 threads = 4 waves (2x2), each wave 64x64.
__global__ __launch_bounds__(256) void k_gemm(const float* __restrict__ enc,
                                              const unsigned short* __restrict__ whb,
                                              const float* __restrict__ sbias,
                                              const float* __restrict__ vvec,
                                              float* __restrict__ scores) {
  __shared__ alignas(16) float As[128 * 32];          // fp32, xor-swizzled 16B slots
  __shared__ alignas(16) unsigned short Bs[128 * 32]; // bf16, xor-swizzled 16B slots

  const int tid = threadIdx.x;
  const int wid = tid >> 6;
  const int lane = tid & 63;

  // grid swizzle: all 8 N-tiles of one M-tile land on the same XCD (flat%8)
  const int flat = blockIdx.x;
  const int nt = (flat >> 3) & 7;
  const int mt = (flat & 7) | ((flat >> 6) << 3);
  const int m_base = mt * 128, n_base = nt * 128;
  const int b_idx = m_base >> 11;  // 128 | 2048 so b uniform per block

  // --- staging source pointers (global addresses carry the LDS xor-swizzle) ---
  // A: per wave 4 chunks of 8 rows x 32 floats; lane l -> row l>>3, slot l&7,
  //    fetches kgroup g = (l&7) ^ ((l>>3)&7)  (16B groups within 128B row)
  const int aRow = wid * 32 + (lane >> 3);
  const int aCol = (((lane & 7) ^ ((lane >> 3) & 7)) << 2);
  const float* gA = enc + (size_t)(m_base + aRow) * E_ + aCol;
  // B: per wave 2 chunks of 16 rows x 32 bf16; lane l -> row l>>2, slot l&3,
  //    fetches kgroup g = (l&3) ^ ((l>>3)&3)  (16B groups within 64B row)
  const int bRow = wid * 32 + (lane >> 2);
  const int bCol = (((lane & 3) ^ ((lane >> 3) & 3)) << 3);
  const unsigned short* gB = whb + (size_t)(n_base + bRow) * E_ + bCol;

  float* ldsA = &As[wid * 1024];
  unsigned short* ldsB = &Bs[wid * 1024];

  const int waveM = wid & 1, waveN = wid >> 1;
  const int mrow = waveM * 64 + (lane & 15);
  const int nrow = waveN * 64 + (lane & 15);

  // --- precompute swizzled fragment read pointers (loop-invariant) ---
  const float* aptr0[4];
  const float* aptr1[4];
  const unsigned short* bptr[4];
  {
    const int g0 = (lane >> 4) * 2;  // fp32 16B-kgroup of this quad (and +1)
    const int gb = (lane >> 4);      // bf16 16B-kgroup of this quad
#pragma unroll
    for (int mi = 0; mi < 4; ++mi) {
      int rl = mrow + mi * 16;
      aptr0[mi] = &As[rl * 32 + (((g0) ^ (rl & 7)) << 2)];
      aptr1[mi] = &As[rl * 32 + (((g0 + 1) ^ (rl & 7)) << 2)];
    }
#pragma unroll
    for (int ni = 0; ni < 4; ++ni) {
      int rl = nrow + ni * 16;
      bptr[ni] = &Bs[rl * 32 + ((gb ^ ((rl >> 1) & 3)) << 3)];
    }
  }

  f32x4 acc[4][4] = {};

  for (int kk = 0; kk < E_; kk += 32) {
    __syncthreads();  // previous iteration's LDS reads done
#pragma unroll
    for (int it = 0; it < 4; ++it)
      async_copy16(gA + (size_t)(it * 8) * E_ + kk, ldsA + it * 256);
#pragma unroll
    for (int it = 0; it < 2; ++it)
      async_copy16(gB + (size_t)(it * 16) * E_ + kk, ldsB + it * 512);
    __syncthreads();  // compiler drains vmcnt(0) before barrier -> LDS ready

    short8 bf[4];
#pragma unroll
    for (int ni = 0; ni < 4; ++ni) bf[ni] = *(const short8*)bptr[ni];
#pragma unroll
    for (int mi = 0; mi < 4; ++mi) {
      float4 f0 = *(const float4*)aptr0[mi];
      float4 f1 = *(const float4*)aptr1[mi];
      uint4v pa;
      pa.x = pack_bf16_2(f0.x, f0.y);
      pa.y = pack_bf16_2(f0.z, f0.w);
      pa.z = pack_bf16_2(f1.x, f1.y);
      pa.w = pack_bf16_2(f1.z, f1.w);
      short8 af = __builtin_bit_cast(short8, pa);
#pragma unroll
      for (int ni = 0; ni < 4; ++ni)
        acc[mi][ni] = __builtin_amdgcn_mfma_f32_16x16x32_bf16(af, bf[ni], acc[mi][ni], 0, 0, 0);
    }
  }

  // --- epilogue: partial = sum over this block's 128 n of v[n]*tanh(s+h) ---
  // C/D layout (m89/m91): row m = mi*16 + quad*4 + r, col n = ni*16 + (lane&15)
  float vv[4], sv[4];
#pragma unroll
  for (int ni = 0; ni < 4; ++ni) {
    int n = n_base + nrow + ni * 16;
    vv[ni] = vvec[n];
    sv[ni] = sbias[b_idx * D_ + n];
  }
  const int quad = lane >> 4;
#pragma unroll
  for (int mi = 0; mi < 4; ++mi) {
#pragma unroll
    for (int r = 0; r < 4; ++r) {
      float sum = 0.f;
#pragma unroll
      for (int ni = 0; ni < 4; ++ni)
        sum += vv[ni] * fast_tanh(sv[ni] + acc[mi][ni][r]);
      sum += __shfl_xor(sum, 1, 16);
      sum += __shfl_xor(sum, 2, 16);
      sum += __shfl_xor(sum, 4, 16);
      sum += __shfl_xor(sum, 8, 16);
      if ((lane & 15) == 0)
        atomicAdd(&scores[m_base + waveM * 64 + mi * 16 + quad * 4 + r], sum);
    }
  }
}

// ---------------- kernel 4: softmax over L per b (in-place) -----------------
__global__ __launch_bounds__(256) void k_softmax(float* __restrict__ sc) {
  int b = blockIdx.x, tid = threadIdx.x;
  int lane = tid & 63, wid = tid >> 6;
  float* row = sc + (size_t)b * L_;
  float vals[8];
  float mx = -1e30f;
#pragma unroll
  for (int j = 0; j < 8; ++j) { vals[j] = row[tid + j * 256]; mx = fmaxf(mx, vals[j]); }
#pragma unroll
  for (int off = 32; off >= 1; off >>= 1) mx = fmaxf(mx, __shfl_xor(mx, off, 64));
  __shared__ float redm[4], reds[4];
  if (lane == 0) redm[wid] = mx;
  __syncthreads();
  mx = fmaxf(fmaxf(redm[0], redm[1]), fmaxf(redm[2], redm[3]));
  float sum = 0.f;
#pragma unroll
  for (int j = 0; j < 8; ++j) { vals[j] = __expf(vals[j] - mx); sum += vals[j]; }
#pragma unroll
  for (int off = 32; off >= 1; off >>= 1) sum += __shfl_xor(sum, off, 64);
  if (lane == 0) reds[wid] = sum;
  __syncthreads();
  sum = reds[0] + reds[1] + reds[2] + reds[3];
  float inv = 1.0f / sum;
#pragma unroll
  for (int j = 0; j < 8; ++j) row[tid + j * 256] = vals[j] * inv;
}

// ---------------- kernel 5: ctx[b][e] = sum_l attn[b][l] * enc[b][l][e] -----
// grid (16 l-chunks of 128, 32 b); 256 threads cover E=2048 as 2x float4 each
__global__ __launch_bounds__(256) void k_ctx(const float* __restrict__ enc,
                                             const float* __restrict__ attn,
                                             float* __restrict__ ctx) {
  int b = blockIdx.y, lc = blockIdx.x;
  int t = threadIdx.x;
  __shared__ float aw[128];
  if (t < 128) aw[t] = attn[(size_t)b * L_ + lc * 128 + t];
  __syncthreads();
  const float* base = enc + ((size_t)b * L_ + (size_t)lc * 128) * E_;
  float4 a0 = make_float4(0.f, 0.f, 0.f, 0.f);
  float4 a1 = make_float4(0.f, 0.f, 0.f, 0.f);
#pragma unroll 2
  for (int l = 0; l < 128; ++l) {
    float w = aw[l];
    const float* r = base + (size_t)l * E_;
    float4 x0 = *(const float4*)(r + t * 4);
    float4 x1 = *(const float4*)(r + 1024 + t * 4);
    a0.x += w * x0.x; a0.y += w * x0.y; a0.z += w * x0.z; a0.w += w * x0.w;
    a1.x += w * x1.x; a1.y += w * x1.y; a1.z += w * x1.z; a1.w += w * x1.w;
  }
  float* cb = ctx + (size_t)b * E_;
  atomicAdd(cb + t * 4 + 0, a0.x);
  atomicAdd(cb + t * 4 + 1, a0.y);
  atomicAdd(cb + t * 4 + 2, a0.z);
  atomicAdd(cb + t * 4 + 3, a0.w);
  atomicAdd(cb + 1024 + t * 4 + 0, a1.x);
  atomicAdd(cb + 1024 + t * 4 + 1, a1.y);
  atomicAdd(cb + 1024 + t * 4 + 2, a1.z);
  atomicAdd(cb + 1024 + t * 4 + 3, a1.w);
}

extern "C" void kernel_launch(void* const* d_in, const int* in_sizes, int n_in,
                              void* d_out, int out_size, void* d_ws, size_t ws_size,
                              hipStream_t stream) {
  const float* dec = (const float*)d_in[0];  // [32,1024]
  const float* enc = (const float*)d_in[1];  // [32,2048,2048]
  const float* Ws  = (const float*)d_in[2];  // [1024,1024]
  const float* Wh  = (const float*)d_in[3];  // [1024,2048]
  const float* v   = (const float*)d_in[4];  // [1024]

  float* ctx  = (float*)d_out;                   // [32,2048]
  float* attn = (float*)d_out + B_ * E_;         // [32,2048]; also scores scratch

  // workspace: W_h in bf16 (4 MB) + s (128 KB)
  unsigned short* whb = (unsigned short*)d_ws;
  float* sbuf = (float*)((char*)d_ws + (size_t)D_ * E_ * sizeof(unsigned short));

  // zero ctx + scores (both accumulated via atomics)
  hipMemsetAsync(d_out, 0, (size_t)out_size * sizeof(float), stream);

  k_s<<<dim3((B_ * D_) / 4), dim3(256), 0, stream>>>(dec, Ws, sbuf);
  k_cvt<<<dim3((D_ * E_) / (256 * 8)), dim3(256), 0, stream>>>(Wh, whb);
  k_gemm<<<dim3((B_ * L_ / 128) * (D_ / 128)), dim3(256), 0, stream>>>(enc, whb, sbuf, v, attn);
  k_softmax<<<dim3(B_), dim3(256), 0, stream>>>(attn);
  k_ctx<<<dim3(L_ / 128, B_), dim3(256), 0, stream>>>(enc, attn, ctx);
}